// Round 18
// baseline (117.538 us; speedup 1.0000x reference)
//
#include <hip/hip_runtime.h>

// Problem constants (from reference)
#define N_NODES 50000
#define N_EDGES 800000
#define IN_CH   128
#define HID_CH  128
#define OUT_CH  64

#define GEMM1_TILES 782          // ceil(50000/64)
#define NR 49                    // node ranges of 1024
#define EB 391                   // edge blocks (2048 edges each)

typedef __attribute__((ext_vector_type(8))) short v8s;
typedef __attribute__((ext_vector_type(4))) float v4f;

// ---------------------------------------------------------------------------
// bf16 helpers (RNE)
__device__ __forceinline__ unsigned bf16rne(float f) {
  unsigned u = __float_as_uint(f);
  return (u + 0x7fffu + ((u >> 16) & 1u)) >> 16;
}
__device__ __forceinline__ unsigned pack2bf(float a, float b) {
  return bf16rne(a) | (bf16rne(b) << 16);
}
__device__ __forceinline__ float bfhi_to_f(unsigned u) {
  return __uint_as_float(u & 0xffff0000u);
}
__device__ __forceinline__ float bflo_to_f(unsigned u) {
  return __uint_as_float(u << 16);
}

// 64-lane exclusive scan (wave)
__device__ __forceinline__ int wave_excl_scan(int v, int lane) {
  int x = v;
#pragma unroll
  for (int off = 1; off < 64; off <<= 1) {
    int y = __shfl_up(x, off);
    if (lane >= off) x += y;
  }
  return x - v;
}

// Accumulate helpers
__device__ __forceinline__ void acc8(uint4 u, float w, float* a) {
  a[0] = fmaf(bflo_to_f(u.x), w, a[0]); a[1] = fmaf(bfhi_to_f(u.x), w, a[1]);
  a[2] = fmaf(bflo_to_f(u.y), w, a[2]); a[3] = fmaf(bfhi_to_f(u.y), w, a[3]);
  a[4] = fmaf(bflo_to_f(u.z), w, a[4]); a[5] = fmaf(bfhi_to_f(u.z), w, a[5]);
  a[6] = fmaf(bflo_to_f(u.w), w, a[6]); a[7] = fmaf(bfhi_to_f(u.w), w, a[7]);
}
__device__ __forceinline__ void acc4(uint2 u, float w, float* a) {
  a[0] = fmaf(bflo_to_f(u.x), w, a[0]); a[1] = fmaf(bfhi_to_f(u.x), w, a[1]);
  a[2] = fmaf(bflo_to_f(u.y), w, a[2]); a[3] = fmaf(bfhi_to_f(u.y), w, a[3]);
}

// ---------------------------------------------------------------------------
// Kernel 1: weight conversion (blocks 0-95) + bucket histogram (blocks 96+).
__global__ __launch_bounds__(256) void inithist_kernel(
    const float* __restrict__ W1, const float* __restrict__ W2,
    unsigned short* __restrict__ Wt1, unsigned short* __restrict__ Wt2,
    const int* __restrict__ dst, int* __restrict__ bcnt) {
  int b = blockIdx.x;
  if (b < 96) {
    int idx = b * 256 + threadIdx.x;
    if (idx < 128 * 128) {
      int k = idx >> 7, c = idx & 127;
      Wt1[c * 128 + k] = (unsigned short)bf16rne(W1[idx]);
    } else if (idx < 128 * 128 + 128 * 64) {
      int i2 = idx - 128 * 128;
      int k = i2 >> 6, c = i2 & 63;
      Wt2[c * 128 + k] = (unsigned short)bf16rne(W2[i2]);
    }
  } else {
    __shared__ int cnt[NR];
    int gid = b - 96;                    // 0..EB-1
    int t = threadIdx.x;
    if (t < NR) cnt[t] = 0;
    __syncthreads();
    long base = ((long)gid * 256 + t) * 8;
    if (base < N_EDGES) {
      int4 d0 = *(const int4*)&dst[base];
      int4 d1 = *(const int4*)&dst[base + 4];
      atomicAdd(&cnt[d0.x >> 10], 1);
      atomicAdd(&cnt[d0.y >> 10], 1);
      atomicAdd(&cnt[d0.z >> 10], 1);
      atomicAdd(&cnt[d0.w >> 10], 1);
      atomicAdd(&cnt[d1.x >> 10], 1);
      atomicAdd(&cnt[d1.y >> 10], 1);
      atomicAdd(&cnt[d1.z >> 10], 1);
      atomicAdd(&cnt[d1.w >> 10], 1);
    }
    __syncthreads();
    if (t < NR) bcnt[gid * NR + t] = cnt[t];
  }
}

// ---------------------------------------------------------------------------
// K2: per-range scan over blocks -> coff, rtot. One wave per range.
__global__ __launch_bounds__(64) void bucket_scan_kernel(
    const int* __restrict__ bcnt, int* __restrict__ coff, int* __restrict__ rtot) {
  int r = blockIdx.x;
  int lane = threadIdx.x;
  int carry = 0;
  for (int c = 0; c < (EB + 63) / 64; ++c) {
    int b = c * 64 + lane;
    int v = (b < EB) ? bcnt[b * NR + r] : 0;
    int ex = wave_excl_scan(v, lane);
    if (b < EB) coff[b * NR + r] = carry + ex;
    carry += __shfl(ex + v, 63);
  }
  if (lane == 0) rtot[r] = carry;
}

// ---------------------------------------------------------------------------
// MFMA GEMM body: both A and B staged in LDS (B-from-global costs ~25us:
// x-staging evicts Wt from L1; fragment loads serialize on L2 latency).
template <int N, bool AFP32>
__device__ __forceinline__ void gemm_body(
    int bid, const void* __restrict__ Av, const unsigned short* __restrict__ Bt,
    unsigned short* __restrict__ out, int nrows) {
  constexpr int KP = 136;
  __shared__ unsigned short sA[64 * KP];
  __shared__ unsigned short sB[N * KP];

  const int row0 = bid * 64;
  const int t = threadIdx.x;

  for (int i = t; i < 64 * 16; i += 256) {
    int r = i >> 4, ch = i & 15;
    uint4 v = make_uint4(0u, 0u, 0u, 0u);
    if (row0 + r < nrows) {
      if constexpr (AFP32) {
        const float* A = (const float*)Av;
        float4 f0 = *(const float4*)&A[(long)(row0 + r) * 128 + ch * 8];
        float4 f1 = *(const float4*)&A[(long)(row0 + r) * 128 + ch * 8 + 4];
        v.x = pack2bf(f0.x, f0.y); v.y = pack2bf(f0.z, f0.w);
        v.z = pack2bf(f1.x, f1.y); v.w = pack2bf(f1.z, f1.w);
      } else {
        const unsigned short* A = (const unsigned short*)Av;
        v = *(const uint4*)&A[(long)(row0 + r) * 128 + ch * 8];
      }
    }
    *(uint4*)&sA[r * KP + ch * 8] = v;
  }
  for (int i = t; i < N * 16; i += 256) {
    int r = i >> 4, ch = i & 15;
    *(uint4*)&sB[r * KP + ch * 8] = *(const uint4*)&Bt[(long)r * 128 + ch * 8];
  }
  __syncthreads();

  const int wave = t >> 6, lane = t & 63;
  const int m0 = wave * 16;
  const int lr = lane & 15;
  const int kg = lane >> 4;

  constexpr int NT = N / 16;
  v4f acc[NT];
#pragma unroll
  for (int i = 0; i < NT; ++i) acc[i] = (v4f)(0.f);

#pragma unroll
  for (int ks = 0; ks < 4; ++ks) {
    const int k0 = ks * 32 + kg * 8;
    v8s a = *(const v8s*)&sA[(m0 + lr) * KP + k0];
#pragma unroll
    for (int nt = 0; nt < NT; ++nt) {
      v8s b = *(const v8s*)&sB[(nt * 16 + lr) * KP + k0];
      acc[nt] = __builtin_amdgcn_mfma_f32_16x16x32_bf16(a, b, acc[nt], 0, 0, 0);
    }
  }

#pragma unroll
  for (int nt = 0; nt < NT; ++nt) {
#pragma unroll
    for (int i = 0; i < 4; ++i) {
      int gr = row0 + m0 + kg * 4 + i;
      if (gr < nrows)
        out[(long)gr * N + nt * 16 + lr] = (unsigned short)bf16rne(acc[nt][i]);
    }
  }
}

// ---------------------------------------------------------------------------
// K3 co-scheduled with GEMM1: bid%3<2 -> GEMM1 tile (782); ==2 -> bucket
// scatter block (391, returning LDS atomics on 49 cursors).
__global__ __launch_bounds__(256) void scatter_gemm1_kernel(
    const int* __restrict__ src, const int* __restrict__ dst,
    const int* __restrict__ coff, const int* __restrict__ rtot,
    int2* __restrict__ ebuf,
    const float* __restrict__ x, const unsigned short* __restrict__ Wt1,
    unsigned short* __restrict__ hw1) {
  int g = blockIdx.x / 3;
  int role = blockIdx.x % 3;
  if (role < 2) {
    int tile = g * 2 + role;
    if (tile < GEMM1_TILES)
      gemm_body<128, true>(tile, x, Wt1, hw1, N_NODES);
    return;
  }
  __shared__ int s_base[NR];
  __shared__ int cur[NR];
  int b = g, t = threadIdx.x;
  if (t < 64) {
    int lane = t;
    int v = (lane < NR) ? rtot[lane] : 0;
    int rb = wave_excl_scan(v, lane);
    if (lane < NR) { s_base[lane] = rb + coff[b * NR + lane]; cur[lane] = 0; }
  }
  __syncthreads();
  long base = ((long)b * 256 + t) * 8;
  if (base < N_EDGES) {
    int4 d0 = *(const int4*)&dst[base];
    int4 d1 = *(const int4*)&dst[base + 4];
    int4 s0 = *(const int4*)&src[base];
    int4 s1 = *(const int4*)&src[base + 4];
    int r, p;
    r = d0.x >> 10; p = s_base[r] + atomicAdd(&cur[r], 1); ebuf[p] = make_int2(s0.x, d0.x);
    r = d0.y >> 10; p = s_base[r] + atomicAdd(&cur[r], 1); ebuf[p] = make_int2(s0.y, d0.y);
    r = d0.z >> 10; p = s_base[r] + atomicAdd(&cur[r], 1); ebuf[p] = make_int2(s0.z, d0.z);
    r = d0.w >> 10; p = s_base[r] + atomicAdd(&cur[r], 1); ebuf[p] = make_int2(s0.w, d0.w);
    r = d1.x >> 10; p = s_base[r] + atomicAdd(&cur[r], 1); ebuf[p] = make_int2(s1.x, d1.x);
    r = d1.y >> 10; p = s_base[r] + atomicAdd(&cur[r], 1); ebuf[p] = make_int2(s1.y, d1.y);
    r = d1.z >> 10; p = s_base[r] + atomicAdd(&cur[r], 1); ebuf[p] = make_int2(s1.z, d1.z);
    r = d1.w >> 10; p = s_base[r] + atomicAdd(&cur[r], 1); ebuf[p] = make_int2(s1.w, d1.w);
  }
}

// ---------------------------------------------------------------------------
// K4: per-range CSR finalize: hist -> block scan -> row_ptr + dinv -> place.
__global__ __launch_bounds__(1024) void range_csr_kernel(
    const int2* __restrict__ ebuf, const int* __restrict__ rtot,
    int* __restrict__ row_ptr, float* __restrict__ dinv,
    int* __restrict__ csr_src) {
  __shared__ int cnt[1024];
  __shared__ int sh[1024];
  __shared__ int s_start;
  int r = blockIdx.x, t = threadIdx.x;
  cnt[t] = 0;
  if (t < 64) {
    int lane = t;
    int v = (lane < NR) ? rtot[lane] : 0;
    int rb = wave_excl_scan(v, lane);
    if (lane == r) s_start = rb;
  }
  __syncthreads();
  const int start = s_start;
  const int total = rtot[r];

  for (int i = t; i < total; i += 1024) {
    atomicAdd(&cnt[ebuf[start + i].y & 1023], 1);
  }
  __syncthreads();
  int v = cnt[t];
  sh[t] = v;
  __syncthreads();
  for (int off = 1; off < 1024; off <<= 1) {
    int add = (t >= off) ? sh[t - off] : 0;
    __syncthreads();
    sh[t] += add;
    __syncthreads();
  }
  int excl = sh[t] - v;
  int gn = r * 1024 + t;
  if (gn < N_NODES) {
    row_ptr[gn] = start + excl;
    dinv[gn] = rsqrtf((float)v + 1.0f);
  } else if (gn == N_NODES) {
    row_ptr[gn] = start + excl;
  }
  __syncthreads();
  cnt[t] = start + excl;
  __syncthreads();

  for (int i = t; i < total; i += 1024) {
    int2 e = ebuf[start + i];
    int pos = atomicAdd(&cnt[e.y & 1023], 1);
    csr_src[pos] = e.x;
  }
}

// ---------------------------------------------------------------------------
// FUSED layer-1 aggregation + layer-2 GEMM (round-8 retry, occupancy fixed):
// 1024-thread blocks (16 waves) x 64 nodes. Each wave quarter-wave-aggregates
// 4 nodes (h1 rows -> LDS sH, bf16, identical rounding), then after one
// barrier the 16 waves compute the 64x64 tile as 4x4 MFMA sub-tiles vs
// LDS-staged Wt2, writing hw2 directly. h1 never touches HBM.
__global__ __launch_bounds__(1024) void agg128_gemm2_kernel(
    const int* __restrict__ row_ptr, const int* __restrict__ csr_src,
    const float* __restrict__ dinv, const unsigned* __restrict__ hw,  // hw1 [N][64] u32
    const float* __restrict__ bias,                                   // b1
    const unsigned short* __restrict__ Wt2,                           // [64][128] bf16
    unsigned short* __restrict__ hw2) {
  constexpr int KP = 136;
  __shared__ unsigned short sH[64 * KP];
  __shared__ unsigned short sB[64 * KP];

  const int t = threadIdx.x;
  const int n0 = blockIdx.x * 64;
  const int wave = t >> 6, lane = t & 63;

  // Stage Wt2 (64 rows x 16 chunks of 16B) — one pass with 1024 threads
  if (t < 64 * 16) {
    int r = t >> 4, ch = t & 15;
    *(uint4*)&sB[r * KP + ch * 8] = *(const uint4*)&Wt2[(long)r * 128 + ch * 8];
  }

  const int q  = lane >> 4;        // edge slot in group of 4
  const int lc = lane & 15;        // channel octet

  // ---- Aggregation: each wave owns 4 consecutive nodes ----
  for (int s = 0; s < 4; ++s) {
    const int row = wave * 4 + s;
    const int n = n0 + row;
    float o[8] = {0.f, 0.f, 0.f, 0.f, 0.f, 0.f, 0.f, 0.f};
    if (n < N_NODES) {
      const int start = row_ptr[n];
      const int deg = row_ptr[n + 1] - start;
      const int ng = (deg + 3) >> 2;
      float a[8] = {0.f, 0.f, 0.f, 0.f, 0.f, 0.f, 0.f, 0.f};

#define LS(i, pp) { int tt = 4 * (pp) + q; int cl = tt < deg ? tt : deg - 1; \
                    s##i = csr_src[start + cl]; m##i = (tt < deg) ? 1.f : 0.f; }
      int s0, s1, s2, s3;
      float m0, m1, m2, m3;
      if (ng > 0) { LS(0, 0) LS(1, 1) LS(2, 2) LS(3, 3) }
      for (int p = 0; p < ng; p += 4) {
        int e0 = s0, e1 = s1, e2 = s2, e3 = s3;
        float f0 = m0, f1 = m1, f2 = m2, f3 = m3;
        int pn = p + 4;
        if (pn < ng) { LS(0, pn) LS(1, pn + 1) LS(2, pn + 2) LS(3, pn + 3) }
        float w0 = dinv[e0] * f0;
        float w1 = dinv[e1] * f1;
        float w2 = dinv[e2] * f2;
        float w3 = dinv[e3] * f3;
        uint4 u0 = *(const uint4*)&hw[(long)e0 * 64 + 4 * lc];
        uint4 u1 = *(const uint4*)&hw[(long)e1 * 64 + 4 * lc];
        uint4 u2 = *(const uint4*)&hw[(long)e2 * 64 + 4 * lc];
        uint4 u3 = *(const uint4*)&hw[(long)e3 * 64 + 4 * lc];
        acc8(u0, w0, a); acc8(u1, w1, a); acc8(u2, w2, a); acc8(u3, w3, a);
      }
#undef LS

#pragma unroll
      for (int i = 0; i < 8; ++i) a[i] += __shfl_xor(a[i], 16);
#pragma unroll
      for (int i = 0; i < 8; ++i) a[i] += __shfl_xor(a[i], 32);

      float dn = dinv[n];
      float sn = dn * dn;
      uint4 uh = *(const uint4*)&hw[(long)n * 64 + 4 * lc];
      float4 ba = *(const float4*)&bias[8 * lc];
      float4 bb = *(const float4*)&bias[8 * lc + 4];
      o[0] = fmaxf(fmaf(bflo_to_f(uh.x), sn, a[0] * dn) + ba.x, 0.f);
      o[1] = fmaxf(fmaf(bfhi_to_f(uh.x), sn, a[1] * dn) + ba.y, 0.f);
      o[2] = fmaxf(fmaf(bflo_to_f(uh.y), sn, a[2] * dn) + ba.z, 0.f);
      o[3] = fmaxf(fmaf(bfhi_to_f(uh.y), sn, a[3] * dn) + ba.w, 0.f);
      o[4] = fmaxf(fmaf(bflo_to_f(uh.z), sn, a[4] * dn) + bb.x, 0.f);
      o[5] = fmaxf(fmaf(bfhi_to_f(uh.z), sn, a[5] * dn) + bb.y, 0.f);
      o[6] = fmaxf(fmaf(bflo_to_f(uh.w), sn, a[6] * dn) + bb.z, 0.f);
      o[7] = fmaxf(fmaf(bfhi_to_f(uh.w), sn, a[7] * dn) + bb.w, 0.f);
    }
    if (q == 0) {
      uint4 pz;
      pz.x = pack2bf(o[0], o[1]);
      pz.y = pack2bf(o[2], o[3]);
      pz.z = pack2bf(o[4], o[5]);
      pz.w = pack2bf(o[6], o[7]);
      *(uint4*)&sH[row * KP + 8 * lc] = pz;
    }
  }
  __syncthreads();  // sH + sB complete

  // ---- MFMA: wave w -> row-tile (w>>2), col-tile (w&3); 16x16 x K=128 ----
  const int mrow = (wave >> 2) * 16;
  const int ct   = (wave & 3) * 16;
  const int lr = lane & 15;
  const int kg = lane >> 4;
  v4f acc = (v4f)(0.f);
#pragma unroll
  for (int ks = 0; ks < 4; ++ks) {
    const int k0 = ks * 32 + kg * 8;
    v8s a = *(const v8s*)&sH[(mrow + lr) * KP + k0];
    v8s b = *(const v8s*)&sB[(ct + lr) * KP + k0];
    acc = __builtin_amdgcn_mfma_f32_16x16x32_bf16(a, b, acc, 0, 0, 0);
  }
#pragma unroll
  for (int i = 0; i < 4; ++i) {
    int gr = n0 + mrow + kg * 4 + i;
    if (gr < N_NODES)
      hw2[(long)gr * 64 + ct + lr] = (unsigned short)bf16rne(acc[i]);
  }
}

// ---------------------------------------------------------------------------
// Layer-2 aggregation (quarter-wave): lane loads 8B = 4 channels; fp32 out.
__global__ __launch_bounds__(256) void agg64_kernel(
    const int* __restrict__ row_ptr, const int* __restrict__ csr_src,
    const float* __restrict__ dinv, const unsigned* __restrict__ hw,
    const float* __restrict__ bias, float* __restrict__ out) {
  int n = (blockIdx.x * 256 + threadIdx.x) >> 6;
  int lane = threadIdx.x & 63;
  if (n >= N_NODES) return;
  const int q  = lane >> 4;
  const int lc = lane & 15;
  const int start = row_ptr[n];
  const int deg = row_ptr[n + 1] - start;
  const int ng = (deg + 3) >> 2;

  float a[4] = {0.f, 0.f, 0.f, 0.f};

#define LS(i, pp) { int tt = 4 * (pp) + q; int cl = tt < deg ? tt : deg - 1; \
                    s##i = csr_src[start + cl]; m##i = (tt < deg) ? 1.f : 0.f; }
  int s0, s1, s2, s3;
  float m0, m1, m2, m3;
  if (ng > 0) { LS(0, 0) LS(1, 1) LS(2, 2) LS(3, 3) }
  for (int p = 0; p < ng; p += 4) {
    int e0 = s0, e1 = s1, e2 = s2, e3 = s3;
    float f0 = m0, f1 = m1, f2 = m2, f3 = m3;
    int pn = p + 4;
    if (pn < ng) { LS(0, pn) LS(1, pn + 1) LS(2, pn + 2) LS(3, pn + 3) }
    float w0 = dinv[e0] * f0;
    float w1 = dinv[e1] * f1;
    float w2 = dinv[e2] * f2;
    float w3 = dinv[e3] * f3;
    uint2 u0 = *(const uint2*)&hw[(long)e0 * 32 + 2 * lc];
    uint2 u1 = *(const uint2*)&hw[(long)e1 * 32 + 2 * lc];
    uint2 u2 = *(const uint2*)&hw[(long)e2 * 32 + 2 * lc];
    uint2 u3 = *(const uint2*)&hw[(long)e3 * 32 + 2 * lc];
    acc4(u0, w0, a); acc4(u1, w1, a); acc4(u2, w2, a); acc4(u3, w3, a);
  }
#undef LS

#pragma unroll
  for (int i = 0; i < 4; ++i) a[i] += __shfl_xor(a[i], 16);
#pragma unroll
  for (int i = 0; i < 4; ++i) a[i] += __shfl_xor(a[i], 32);

  float dn = dinv[n];
  float sn = dn * dn;
  uint2 uh = *(const uint2*)&hw[(long)n * 32 + 2 * lc];
  float4 bb = *(const float4*)&bias[4 * lc];
  float o0 = fmaxf(fmaf(bflo_to_f(uh.x), sn, a[0] * dn) + bb.x, 0.f);
  float o1 = fmaxf(fmaf(bfhi_to_f(uh.x), sn, a[1] * dn) + bb.y, 0.f);
  float o2 = fmaxf(fmaf(bflo_to_f(uh.y), sn, a[2] * dn) + bb.z, 0.f);
  float o3 = fmaxf(fmaf(bfhi_to_f(uh.y), sn, a[3] * dn) + bb.w, 0.f);
  if (q == 0) {
    *(float4*)&out[(long)n * 64 + 4 * lc] = make_float4(o0, o1, o2, o3);
  }
}

// ---------------------------------------------------------------------------
extern "C" void kernel_launch(void* const* d_in, const int* in_sizes, int n_in,
                              void* d_out, int out_size, void* d_ws, size_t ws_size,
                              hipStream_t stream) {
  const float* x  = (const float*)d_in[0];
  const int*   ei = (const int*)d_in[1];
  const float* W1 = (const float*)d_in[2];
  const float* b1 = (const float*)d_in[3];
  const float* W2 = (const float*)d_in[4];
  const float* b2 = (const float*)d_in[5];
  float* out = (float*)d_out;

  const int* src = ei;             // edge_index[0]
  const int* dst = ei + N_EDGES;   // edge_index[1]

  // Workspace layout
  char* ws = (char*)d_ws;
  int*   bcnt    = (int*)ws;                     ws += 19200 * 4;
  int*   coff    = (int*)ws;                     ws += 19200 * 4;
  int*   rtot    = (int*)ws;                     ws += 64 * 4;
  int*   row_ptr = (int*)ws;                     ws += 50048 * 4;
  float* dinv    = (float*)ws;                   ws += 50048 * 4;
  int2*  ebuf    = (int2*)ws;                    ws += (size_t)N_EDGES * 8;
  int*   csr_src = (int*)ws;                     ws += (size_t)N_EDGES * 4;
  unsigned short* Wt1 = (unsigned short*)ws;     ws += 128 * 128 * 2;
  unsigned short* Wt2 = (unsigned short*)ws;     ws += 64 * 128 * 2;
  unsigned short* hw1 = (unsigned short*)ws;     ws += (size_t)N_NODES * 128 * 2;
  unsigned short* hw2 = (unsigned short*)ws;     ws += (size_t)N_NODES * 64 * 2;

  // ---- 1: weight conversion + bucket histogram ----
  inithist_kernel<<<96 + EB, 256, 0, stream>>>(W1, W2, Wt1, Wt2, dst, bcnt);

  // ---- 2: per-range block scan ----
  bucket_scan_kernel<<<NR, 64, 0, stream>>>(bcnt, coff, rtot);

  // ---- 3: bucket scatter co-scheduled with GEMM1 ----
  scatter_gemm1_kernel<<<GEMM1_TILES / 2 * 3, 256, 0, stream>>>(
      src, dst, coff, rtot, ebuf, x, Wt1, hw1);

  // ---- 4: per-range CSR finalize ----
  range_csr_kernel<<<NR, 1024, 0, stream>>>(ebuf, rtot, row_ptr, dinv, csr_src);

  // ---- 5: fused layer-1 aggregation + layer-2 GEMM ----
  agg128_gemm2_kernel<<<GEMM1_TILES, 1024, 0, stream>>>(
      row_ptr, csr_src, dinv, (const unsigned*)hw1, b1, Wt2, hw2);

  // ---- 6: layer-2 aggregation ----
  agg64_kernel<<<(N_NODES * 64 + 255) / 256, 256, 0, stream>>>(
      row_ptr, csr_src, dinv, (const unsigned*)hw2, b2, out);
}

// Round 19
// 108.848 us; speedup vs baseline: 1.0798x; 1.0798x over previous
//
#include <hip/hip_runtime.h>

// Problem constants (from reference)
#define N_NODES 50000
#define N_EDGES 800000
#define IN_CH   128
#define HID_CH  128
#define OUT_CH  64

#define GEMM1_TILES 782          // ceil(50000/64)
#define NR 49                    // node ranges of 1024
#define EB 391                   // edge blocks (2048 edges each)

typedef __attribute__((ext_vector_type(8))) short v8s;
typedef __attribute__((ext_vector_type(4))) float v4f;

// ---------------------------------------------------------------------------
// bf16 helpers (RNE)
__device__ __forceinline__ unsigned bf16rne(float f) {
  unsigned u = __float_as_uint(f);
  return (u + 0x7fffu + ((u >> 16) & 1u)) >> 16;
}
__device__ __forceinline__ unsigned pack2bf(float a, float b) {
  return bf16rne(a) | (bf16rne(b) << 16);
}
__device__ __forceinline__ float bfhi_to_f(unsigned u) {
  return __uint_as_float(u & 0xffff0000u);
}
__device__ __forceinline__ float bflo_to_f(unsigned u) {
  return __uint_as_float(u << 16);
}

// 64-lane exclusive scan (wave)
__device__ __forceinline__ int wave_excl_scan(int v, int lane) {
  int x = v;
#pragma unroll
  for (int off = 1; off < 64; off <<= 1) {
    int y = __shfl_up(x, off);
    if (lane >= off) x += y;
  }
  return x - v;
}

// Accumulate helpers
__device__ __forceinline__ void acc8(uint4 u, float w, float* a) {
  a[0] = fmaf(bflo_to_f(u.x), w, a[0]); a[1] = fmaf(bfhi_to_f(u.x), w, a[1]);
  a[2] = fmaf(bflo_to_f(u.y), w, a[2]); a[3] = fmaf(bfhi_to_f(u.y), w, a[3]);
  a[4] = fmaf(bflo_to_f(u.z), w, a[4]); a[5] = fmaf(bfhi_to_f(u.z), w, a[5]);
  a[6] = fmaf(bflo_to_f(u.w), w, a[6]); a[7] = fmaf(bfhi_to_f(u.w), w, a[7]);
}
__device__ __forceinline__ void acc4(uint2 u, float w, float* a) {
  a[0] = fmaf(bflo_to_f(u.x), w, a[0]); a[1] = fmaf(bfhi_to_f(u.x), w, a[1]);
  a[2] = fmaf(bflo_to_f(u.y), w, a[2]); a[3] = fmaf(bfhi_to_f(u.y), w, a[3]);
}

// ---------------------------------------------------------------------------
// Kernel 1: weight conversion (blocks 0-95) + bucket histogram (blocks 96+).
__global__ __launch_bounds__(256) void inithist_kernel(
    const float* __restrict__ W1, const float* __restrict__ W2,
    unsigned short* __restrict__ Wt1, unsigned short* __restrict__ Wt2,
    const int* __restrict__ dst, int* __restrict__ bcnt) {
  int b = blockIdx.x;
  if (b < 96) {
    int idx = b * 256 + threadIdx.x;
    if (idx < 128 * 128) {
      int k = idx >> 7, c = idx & 127;
      Wt1[c * 128 + k] = (unsigned short)bf16rne(W1[idx]);
    } else if (idx < 128 * 128 + 128 * 64) {
      int i2 = idx - 128 * 128;
      int k = i2 >> 6, c = i2 & 63;
      Wt2[c * 128 + k] = (unsigned short)bf16rne(W2[i2]);
    }
  } else {
    __shared__ int cnt[NR];
    int gid = b - 96;                    // 0..EB-1
    int t = threadIdx.x;
    if (t < NR) cnt[t] = 0;
    __syncthreads();
    long base = ((long)gid * 256 + t) * 8;
    if (base < N_EDGES) {
      int4 d0 = *(const int4*)&dst[base];
      int4 d1 = *(const int4*)&dst[base + 4];
      atomicAdd(&cnt[d0.x >> 10], 1);
      atomicAdd(&cnt[d0.y >> 10], 1);
      atomicAdd(&cnt[d0.z >> 10], 1);
      atomicAdd(&cnt[d0.w >> 10], 1);
      atomicAdd(&cnt[d1.x >> 10], 1);
      atomicAdd(&cnt[d1.y >> 10], 1);
      atomicAdd(&cnt[d1.z >> 10], 1);
      atomicAdd(&cnt[d1.w >> 10], 1);
    }
    __syncthreads();
    if (t < NR) bcnt[gid * NR + t] = cnt[t];
  }
}

// ---------------------------------------------------------------------------
// K2: per-range scan over blocks -> coff, rtot. One wave per range.
__global__ __launch_bounds__(64) void bucket_scan_kernel(
    const int* __restrict__ bcnt, int* __restrict__ coff, int* __restrict__ rtot) {
  int r = blockIdx.x;
  int lane = threadIdx.x;
  int carry = 0;
  for (int c = 0; c < (EB + 63) / 64; ++c) {
    int b = c * 64 + lane;
    int v = (b < EB) ? bcnt[b * NR + r] : 0;
    int ex = wave_excl_scan(v, lane);
    if (b < EB) coff[b * NR + r] = carry + ex;
    carry += __shfl(ex + v, 63);
  }
  if (lane == 0) rtot[r] = carry;
}

// ---------------------------------------------------------------------------
// MFMA GEMM body: both A and B staged in LDS (B-from-global costs ~25us:
// x-staging evicts Wt from L1; fragment loads serialize on L2 latency).
template <int N, bool AFP32>
__device__ __forceinline__ void gemm_body(
    int bid, const void* __restrict__ Av, const unsigned short* __restrict__ Bt,
    unsigned short* __restrict__ out, int nrows) {
  constexpr int KP = 136;
  __shared__ unsigned short sA[64 * KP];
  __shared__ unsigned short sB[N * KP];

  const int row0 = bid * 64;
  const int t = threadIdx.x;

  for (int i = t; i < 64 * 16; i += 256) {
    int r = i >> 4, ch = i & 15;
    uint4 v = make_uint4(0u, 0u, 0u, 0u);
    if (row0 + r < nrows) {
      if constexpr (AFP32) {
        const float* A = (const float*)Av;
        float4 f0 = *(const float4*)&A[(long)(row0 + r) * 128 + ch * 8];
        float4 f1 = *(const float4*)&A[(long)(row0 + r) * 128 + ch * 8 + 4];
        v.x = pack2bf(f0.x, f0.y); v.y = pack2bf(f0.z, f0.w);
        v.z = pack2bf(f1.x, f1.y); v.w = pack2bf(f1.z, f1.w);
      } else {
        const unsigned short* A = (const unsigned short*)Av;
        v = *(const uint4*)&A[(long)(row0 + r) * 128 + ch * 8];
      }
    }
    *(uint4*)&sA[r * KP + ch * 8] = v;
  }
  for (int i = t; i < N * 16; i += 256) {
    int r = i >> 4, ch = i & 15;
    *(uint4*)&sB[r * KP + ch * 8] = *(const uint4*)&Bt[(long)r * 128 + ch * 8];
  }
  __syncthreads();

  const int wave = t >> 6, lane = t & 63;
  const int m0 = wave * 16;
  const int lr = lane & 15;
  const int kg = lane >> 4;

  constexpr int NT = N / 16;
  v4f acc[NT];
#pragma unroll
  for (int i = 0; i < NT; ++i) acc[i] = (v4f)(0.f);

#pragma unroll
  for (int ks = 0; ks < 4; ++ks) {
    const int k0 = ks * 32 + kg * 8;
    v8s a = *(const v8s*)&sA[(m0 + lr) * KP + k0];
#pragma unroll
    for (int nt = 0; nt < NT; ++nt) {
      v8s b = *(const v8s*)&sB[(nt * 16 + lr) * KP + k0];
      acc[nt] = __builtin_amdgcn_mfma_f32_16x16x32_bf16(a, b, acc[nt], 0, 0, 0);
    }
  }

#pragma unroll
  for (int nt = 0; nt < NT; ++nt) {
#pragma unroll
    for (int i = 0; i < 4; ++i) {
      int gr = row0 + m0 + kg * 4 + i;
      if (gr < nrows)
        out[(long)gr * N + nt * 16 + lr] = (unsigned short)bf16rne(acc[nt][i]);
    }
  }
}

// ---------------------------------------------------------------------------
// K3 co-scheduled with GEMM1: bid%3<2 -> GEMM1 tile (782); ==2 -> bucket
// scatter block (391, returning LDS atomics on 49 cursors).
__global__ __launch_bounds__(256) void scatter_gemm1_kernel(
    const int* __restrict__ src, const int* __restrict__ dst,
    const int* __restrict__ coff, const int* __restrict__ rtot,
    int2* __restrict__ ebuf,
    const float* __restrict__ x, const unsigned short* __restrict__ Wt1,
    unsigned short* __restrict__ hw1) {
  int g = blockIdx.x / 3;
  int role = blockIdx.x % 3;
  if (role < 2) {
    int tile = g * 2 + role;
    if (tile < GEMM1_TILES)
      gemm_body<128, true>(tile, x, Wt1, hw1, N_NODES);
    return;
  }
  __shared__ int s_base[NR];
  __shared__ int cur[NR];
  int b = g, t = threadIdx.x;
  if (t < 64) {
    int lane = t;
    int v = (lane < NR) ? rtot[lane] : 0;
    int rb = wave_excl_scan(v, lane);
    if (lane < NR) { s_base[lane] = rb + coff[b * NR + lane]; cur[lane] = 0; }
  }
  __syncthreads();
  long base = ((long)b * 256 + t) * 8;
  if (base < N_EDGES) {
    int4 d0 = *(const int4*)&dst[base];
    int4 d1 = *(const int4*)&dst[base + 4];
    int4 s0 = *(const int4*)&src[base];
    int4 s1 = *(const int4*)&src[base + 4];
    int r, p;
    r = d0.x >> 10; p = s_base[r] + atomicAdd(&cur[r], 1); ebuf[p] = make_int2(s0.x, d0.x);
    r = d0.y >> 10; p = s_base[r] + atomicAdd(&cur[r], 1); ebuf[p] = make_int2(s0.y, d0.y);
    r = d0.z >> 10; p = s_base[r] + atomicAdd(&cur[r], 1); ebuf[p] = make_int2(s0.z, d0.z);
    r = d0.w >> 10; p = s_base[r] + atomicAdd(&cur[r], 1); ebuf[p] = make_int2(s0.w, d0.w);
    r = d1.x >> 10; p = s_base[r] + atomicAdd(&cur[r], 1); ebuf[p] = make_int2(s1.x, d1.x);
    r = d1.y >> 10; p = s_base[r] + atomicAdd(&cur[r], 1); ebuf[p] = make_int2(s1.y, d1.y);
    r = d1.z >> 10; p = s_base[r] + atomicAdd(&cur[r], 1); ebuf[p] = make_int2(s1.z, d1.z);
    r = d1.w >> 10; p = s_base[r] + atomicAdd(&cur[r], 1); ebuf[p] = make_int2(s1.w, d1.w);
  }
}

// ---------------------------------------------------------------------------
// K4: per-range CSR finalize: hist -> block scan -> row_ptr + dinv -> place.
__global__ __launch_bounds__(1024) void range_csr_kernel(
    const int2* __restrict__ ebuf, const int* __restrict__ rtot,
    int* __restrict__ row_ptr, float* __restrict__ dinv,
    int* __restrict__ csr_src) {
  __shared__ int cnt[1024];
  __shared__ int sh[1024];
  __shared__ int s_start;
  int r = blockIdx.x, t = threadIdx.x;
  cnt[t] = 0;
  if (t < 64) {
    int lane = t;
    int v = (lane < NR) ? rtot[lane] : 0;
    int rb = wave_excl_scan(v, lane);
    if (lane == r) s_start = rb;
  }
  __syncthreads();
  const int start = s_start;
  const int total = rtot[r];

  for (int i = t; i < total; i += 1024) {
    atomicAdd(&cnt[ebuf[start + i].y & 1023], 1);
  }
  __syncthreads();
  int v = cnt[t];
  sh[t] = v;
  __syncthreads();
  for (int off = 1; off < 1024; off <<= 1) {
    int add = (t >= off) ? sh[t - off] : 0;
    __syncthreads();
    sh[t] += add;
    __syncthreads();
  }
  int excl = sh[t] - v;
  int gn = r * 1024 + t;
  if (gn < N_NODES) {
    row_ptr[gn] = start + excl;
    dinv[gn] = rsqrtf((float)v + 1.0f);
  } else if (gn == N_NODES) {
    row_ptr[gn] = start + excl;
  }
  __syncthreads();
  cnt[t] = start + excl;
  __syncthreads();

  for (int i = t; i < total; i += 1024) {
    int2 e = ebuf[start + i];
    int pos = atomicAdd(&cnt[e.y & 1023], 1);
    csr_src[pos] = e.x;
  }
}

// ---------------------------------------------------------------------------
// Standalone GEMM2 wrapper
__global__ __launch_bounds__(256) void gemm2_kernel(
    const unsigned short* __restrict__ A, const unsigned short* __restrict__ Wt2,
    unsigned short* __restrict__ hw2) {
  gemm_body<64, false>(blockIdx.x, A, Wt2, hw2, N_NODES);
}

// ---------------------------------------------------------------------------
// Layer-1 aggregation (quarter-wave: 4 edges per VMEM instruction)
__global__ __launch_bounds__(256) void agg128_kernel(
    const int* __restrict__ row_ptr, const int* __restrict__ csr_src,
    const float* __restrict__ dinv, const unsigned* __restrict__ hw,
    const float* __restrict__ bias, unsigned* __restrict__ h1out) {
  int n = (blockIdx.x * 256 + threadIdx.x) >> 6;
  int lane = threadIdx.x & 63;
  if (n >= N_NODES) return;
  const int q  = lane >> 4;
  const int lc = lane & 15;
  const int start = row_ptr[n];
  const int deg = row_ptr[n + 1] - start;
  const int ng = (deg + 3) >> 2;

  float a[8] = {0.f, 0.f, 0.f, 0.f, 0.f, 0.f, 0.f, 0.f};

#define LS(i, pp) { int tt = 4 * (pp) + q; int cl = tt < deg ? tt : deg - 1; \
                    s##i = csr_src[start + cl]; m##i = (tt < deg) ? 1.f : 0.f; }
  int s0, s1, s2, s3;
  float m0, m1, m2, m3;
  if (ng > 0) { LS(0, 0) LS(1, 1) LS(2, 2) LS(3, 3) }
  for (int p = 0; p < ng; p += 4) {
    int e0 = s0, e1 = s1, e2 = s2, e3 = s3;
    float f0 = m0, f1 = m1, f2 = m2, f3 = m3;
    int pn = p + 4;
    if (pn < ng) { LS(0, pn) LS(1, pn + 1) LS(2, pn + 2) LS(3, pn + 3) }
    float w0 = dinv[e0] * f0;
    float w1 = dinv[e1] * f1;
    float w2 = dinv[e2] * f2;
    float w3 = dinv[e3] * f3;
    uint4 u0 = *(const uint4*)&hw[(long)e0 * 64 + 4 * lc];
    uint4 u1 = *(const uint4*)&hw[(long)e1 * 64 + 4 * lc];
    uint4 u2 = *(const uint4*)&hw[(long)e2 * 64 + 4 * lc];
    uint4 u3 = *(const uint4*)&hw[(long)e3 * 64 + 4 * lc];
    acc8(u0, w0, a); acc8(u1, w1, a); acc8(u2, w2, a); acc8(u3, w3, a);
  }
#undef LS

#pragma unroll
  for (int i = 0; i < 8; ++i) a[i] += __shfl_xor(a[i], 16);
#pragma unroll
  for (int i = 0; i < 8; ++i) a[i] += __shfl_xor(a[i], 32);

  float dn = dinv[n];
  float sn = dn * dn;
  uint4 uh = *(const uint4*)&hw[(long)n * 64 + 4 * lc];
  float4 ba = *(const float4*)&bias[8 * lc];
  float4 bb = *(const float4*)&bias[8 * lc + 4];
  float o0 = fmaxf(fmaf(bflo_to_f(uh.x), sn, a[0] * dn) + ba.x, 0.f);
  float o1 = fmaxf(fmaf(bfhi_to_f(uh.x), sn, a[1] * dn) + ba.y, 0.f);
  float o2 = fmaxf(fmaf(bflo_to_f(uh.y), sn, a[2] * dn) + ba.z, 0.f);
  float o3 = fmaxf(fmaf(bfhi_to_f(uh.y), sn, a[3] * dn) + ba.w, 0.f);
  float o4 = fmaxf(fmaf(bflo_to_f(uh.z), sn, a[4] * dn) + bb.x, 0.f);
  float o5 = fmaxf(fmaf(bfhi_to_f(uh.z), sn, a[5] * dn) + bb.y, 0.f);
  float o6 = fmaxf(fmaf(bflo_to_f(uh.w), sn, a[6] * dn) + bb.z, 0.f);
  float o7 = fmaxf(fmaf(bfhi_to_f(uh.w), sn, a[7] * dn) + bb.w, 0.f);
  if (q == 0) {
    uint4 pz;
    pz.x = pack2bf(o0, o1);
    pz.y = pack2bf(o2, o3);
    pz.z = pack2bf(o4, o5);
    pz.w = pack2bf(o6, o7);
    *(uint4*)&h1out[(long)n * 64 + 4 * lc] = pz;
  }
}

// Layer-2 aggregation (quarter-wave)
__global__ __launch_bounds__(256) void agg64_kernel(
    const int* __restrict__ row_ptr, const int* __restrict__ csr_src,
    const float* __restrict__ dinv, const unsigned* __restrict__ hw,
    const float* __restrict__ bias, float* __restrict__ out) {
  int n = (blockIdx.x * 256 + threadIdx.x) >> 6;
  int lane = threadIdx.x & 63;
  if (n >= N_NODES) return;
  const int q  = lane >> 4;
  const int lc = lane & 15;
  const int start = row_ptr[n];
  const int deg = row_ptr[n + 1] - start;
  const int ng = (deg + 3) >> 2;

  float a[4] = {0.f, 0.f, 0.f, 0.f};

#define LS(i, pp) { int tt = 4 * (pp) + q; int cl = tt < deg ? tt : deg - 1; \
                    s##i = csr_src[start + cl]; m##i = (tt < deg) ? 1.f : 0.f; }
  int s0, s1, s2, s3;
  float m0, m1, m2, m3;
  if (ng > 0) { LS(0, 0) LS(1, 1) LS(2, 2) LS(3, 3) }
  for (int p = 0; p < ng; p += 4) {
    int e0 = s0, e1 = s1, e2 = s2, e3 = s3;
    float f0 = m0, f1 = m1, f2 = m2, f3 = m3;
    int pn = p + 4;
    if (pn < ng) { LS(0, pn) LS(1, pn + 1) LS(2, pn + 2) LS(3, pn + 3) }
    float w0 = dinv[e0] * f0;
    float w1 = dinv[e1] * f1;
    float w2 = dinv[e2] * f2;
    float w3 = dinv[e3] * f3;
    uint2 u0 = *(const uint2*)&hw[(long)e0 * 32 + 2 * lc];
    uint2 u1 = *(const uint2*)&hw[(long)e1 * 32 + 2 * lc];
    uint2 u2 = *(const uint2*)&hw[(long)e2 * 32 + 2 * lc];
    uint2 u3 = *(const uint2*)&hw[(long)e3 * 32 + 2 * lc];
    acc4(u0, w0, a); acc4(u1, w1, a); acc4(u2, w2, a); acc4(u3, w3, a);
  }
#undef LS

#pragma unroll
  for (int i = 0; i < 4; ++i) a[i] += __shfl_xor(a[i], 16);
#pragma unroll
  for (int i = 0; i < 4; ++i) a[i] += __shfl_xor(a[i], 32);

  float dn = dinv[n];
  float sn = dn * dn;
  uint2 uh = *(const uint2*)&hw[(long)n * 32 + 2 * lc];
  float4 bb = *(const float4*)&bias[4 * lc];
  float o0 = fmaxf(fmaf(bflo_to_f(uh.x), sn, a[0] * dn) + bb.x, 0.f);
  float o1 = fmaxf(fmaf(bfhi_to_f(uh.x), sn, a[1] * dn) + bb.y, 0.f);
  float o2 = fmaxf(fmaf(bflo_to_f(uh.y), sn, a[2] * dn) + bb.z, 0.f);
  float o3 = fmaxf(fmaf(bfhi_to_f(uh.y), sn, a[3] * dn) + bb.w, 0.f);
  if (q == 0) {
    *(float4*)&out[(long)n * 64 + 4 * lc] = make_float4(o0, o1, o2, o3);
  }
}

// ---------------------------------------------------------------------------
extern "C" void kernel_launch(void* const* d_in, const int* in_sizes, int n_in,
                              void* d_out, int out_size, void* d_ws, size_t ws_size,
                              hipStream_t stream) {
  const float* x  = (const float*)d_in[0];
  const int*   ei = (const int*)d_in[1];
  const float* W1 = (const float*)d_in[2];
  const float* b1 = (const float*)d_in[3];
  const float* W2 = (const float*)d_in[4];
  const float* b2 = (const float*)d_in[5];
  float* out = (float*)d_out;

  const int* src = ei;             // edge_index[0]
  const int* dst = ei + N_EDGES;   // edge_index[1]

  // Workspace layout
  char* ws = (char*)d_ws;
  int*   bcnt    = (int*)ws;                     ws += 19200 * 4;
  int*   coff    = (int*)ws;                     ws += 19200 * 4;
  int*   rtot    = (int*)ws;                     ws += 64 * 4;
  int*   row_ptr = (int*)ws;                     ws += 50048 * 4;
  float* dinv    = (float*)ws;                   ws += 50048 * 4;
  int2*  ebuf    = (int2*)ws;                    ws += (size_t)N_EDGES * 8;
  int*   csr_src = (int*)ws;                     ws += (size_t)N_EDGES * 4;
  unsigned short* Wt1 = (unsigned short*)ws;     ws += 128 * 128 * 2;
  unsigned short* Wt2 = (unsigned short*)ws;     ws += 64 * 128 * 2;
  unsigned short* hw1 = (unsigned short*)ws;     ws += (size_t)N_NODES * 128 * 2;
  unsigned*       h1  = (unsigned*)ws;           ws += (size_t)N_NODES * 64 * 4;
  unsigned short* hw2 = (unsigned short*)ws;     ws += (size_t)N_NODES * 64 * 2;

  // ---- 1: weight conversion + bucket histogram ----
  inithist_kernel<<<96 + EB, 256, 0, stream>>>(W1, W2, Wt1, Wt2, dst, bcnt);

  // ---- 2: per-range block scan ----
  bucket_scan_kernel<<<NR, 64, 0, stream>>>(bcnt, coff, rtot);

  // ---- 3: bucket scatter co-scheduled with GEMM1 ----
  scatter_gemm1_kernel<<<GEMM1_TILES / 2 * 3, 256, 0, stream>>>(
      src, dst, coff, rtot, ebuf, x, Wt1, hw1);

  // ---- 4: per-range CSR finalize ----
  range_csr_kernel<<<NR, 1024, 0, stream>>>(ebuf, rtot, row_ptr, dinv, csr_src);

  // ---- 5: Layer 1 aggregation ----
  agg128_kernel<<<(N_NODES * 64 + 255) / 256, 256, 0, stream>>>(
      row_ptr, csr_src, dinv, (const unsigned*)hw1, b1, h1);

  // ---- 6: Layer 2 GEMM ----
  gemm2_kernel<<<GEMM1_TILES, 256, 0, stream>>>(
      (const unsigned short*)h1, Wt2, hw2);

  // ---- 7: Layer 2 aggregation ----
  agg64_kernel<<<(N_NODES * 64 + 255) / 256, 256, 0, stream>>>(
      row_ptr, csr_src, dinv, (const unsigned*)hw2, b2, out);
}